// Round 6
// baseline (16680.211 us; speedup 1.0000x reference)
//
#include <hip/hip_runtime.h>
#include <cstdint>

#define BX   32
#define NN   1000
#define FF   16
#define TT   48          // HIST + FC
#define HIST 24
#define FC   24
#define HID  64
#define DEG  16
#define GCIN 18          // F + 2
#define BN   (BX*NN)     // 32000 nodes
#define PADC 146         // enc ct row stride: exact row, 8B-aligned, stride%32=18 -> 2-way (free)
#define PADD 130         // dec ct row stride: 8B-aligned, stride%32=2 -> 2-way (free)
#define PADA 65          // ag row stride

__device__ __forceinline__ float sigf(float x)  { return 1.0f/(1.0f+__expf(-x)); }
__device__ __forceinline__ float tanhf_(float x){ return 2.0f/(1.0f+__expf(-2.0f*x)) - 1.0f; }

// ---------------- pre-pass: static part of the edge aggregation ----------------
// One block per (b,t); X[b][t] slice (64KB) + y (4KB) staged in dynamic LDS, so
// the 16-edge scatter hits LDS instead of HBM/L2. HBM = read-once + write-once.
__global__ __launch_bounds__(1024, 4) void agg_pre(
    const float* __restrict__ X, const float* __restrict__ y,
    const int*   __restrict__ esrc, const float* __restrict__ ew,
    float* __restrict__ aggs)
{
    extern __shared__ float sm[];
    float* Xs = sm;            // [1000][16]
    float* ys = sm + NN*FF;    // [1000]

    const int b = blockIdx.x;  // 0..31
    const int t = blockIdx.y;  // 0..23
    const float* Xt = X + (size_t)(b*TT + t)*NN*FF;
    const float* yt = y + (size_t)(b*TT + t)*NN;

    for (int i = threadIdx.x; i < NN*FF/4; i += 1024)
        ((float4*)Xs)[i] = ((const float4*)Xt)[i];
    for (int i = threadIdx.x; i < NN; i += 1024)
        ys[i] = yt[i];
    __syncthreads();

    const int nl = threadIdx.x;
    if (nl < NN){
        const int node = b*NN + nl;
        float agg[17];
        #pragma unroll
        for (int i=0;i<17;i++) agg[i]=0.f;

        const int e0 = node*DEG;
        const int4*   sv = (const int4*)  (esrc + e0);
        const float4* wv = (const float4*)(ew   + e0);
        #pragma unroll
        for (int q=0;q<4;q++){
            int4   s4 = sv[q];
            float4 w4 = wv[q];
            const int   ss[4] = {s4.x, s4.y, s4.z, s4.w};
            const float ww[4] = {w4.x, w4.y, w4.z, w4.w};
            #pragma unroll
            for (int i=0;i<4;i++){
                const int sl = ss[i] - b*NN;
                const float wgt = ww[i];
                agg[0] += wgt * ys[sl];
                const float4* sr = (const float4*)&Xs[sl*FF];
                #pragma unroll
                for (int q2=0;q2<4;q2++){
                    float4 v = sr[q2];
                    agg[1+4*q2] += wgt*v.x; agg[2+4*q2] += wgt*v.y;
                    agg[3+4*q2] += wgt*v.z; agg[4+4*q2] += wgt*v.w;
                }
            }
        }
        #pragma unroll
        for (int k=0;k<17;k++) aggs[((size_t)t*17 + k)*BN + node] = agg[k];
    }
}

// ---------------- encoder step ----------------
// 512 thr = 8 waves; 64 nodes/block (lane=node), wave = j-octet. grid 500 ->
// 4000 waves (~4/SIMD). All per-node state in LDS row ct[lane] = [xg|conv|h];
// GRU loop keeps only 4 accumulators -> ~60 VGPR, no spills.
__global__ __launch_bounds__(512, 4) void enc_step(
    const float* __restrict__ X, const float* __restrict__ y,
    const int*   __restrict__ esrc, const float* __restrict__ ew,
    const float* __restrict__ aggs,
    const float* __restrict__ W_rel, const float* __restrict__ b_rel,
    const float* __restrict__ W_root,
    const float* __restrict__ Wih, const float* __restrict__ Whh,
    const float* __restrict__ bih, const float* __restrict__ bhh,
    const float* __restrict__ Wout, const float* __restrict__ bout,
    const float* __restrict__ h_in, float* __restrict__ h_out,
    const float* __restrict__ xn_in, float* __restrict__ xn_out,
    int t)
{
    __shared__ float ct[64*PADC];    // [lane][0:18)=xg, [18:82)=conv, [82:146)=h
    __shared__ float ag[18*PADA];    // [k][lane] edge aggregation
    __shared__ float xs[8][64];

    const int lane = threadIdx.x & 63;
    int w = threadIdx.x >> 6;
    w = __builtin_amdgcn_readfirstlane(w);      // wave-uniform -> s_load weights
    const int node = blockIdx.x*64 + lane;
    const int b    = node / NN;
    const int nloc = node - b*NN;
    float* ctl = ct + lane*PADC;

    // ---- P0: stage h (all waves), xg (w0), agf gather (w1) ----
    #pragma unroll
    for (int i=0;i<8;i++){
        const int k = w*8 + i;
        ctl[82+k] = h_in[(size_t)k*BN + node];
    }
    if (w == 0){
        const float* Xt = X + (size_t)(b*TT + t)*NN*FF;
        const float* yt = y + (size_t)(b*TT + t)*NN;
        ctl[0] = xn_in[node];
        ctl[1] = yt[nloc];
        const float4* xr = (const float4*)(Xt + nloc*FF);
        #pragma unroll
        for (int q=0;q<4;q++){
            float4 v = xr[q];
            ctl[2+4*q]=v.x; ctl[3+4*q]=v.y; ctl[4+4*q]=v.z; ctl[5+4*q]=v.w;
        }
    } else if (w == 1){
        float a0 = 0.f;
        const int e0 = node*DEG;
        const int4*   sv = (const int4*)  (esrc + e0);
        const float4* wv = (const float4*)(ew   + e0);
        #pragma unroll
        for (int q=0;q<4;q++){
            int4   s4 = sv[q];
            float4 w4 = wv[q];
            a0 += w4.x * xn_in[s4.x];
            a0 += w4.y * xn_in[s4.y];
            a0 += w4.z * xn_in[s4.z];
            a0 += w4.w * xn_in[s4.w];
        }
        ag[0*PADA + lane] = a0;
        #pragma unroll
        for (int k=0;k<17;k++)
            ag[(1+k)*PADA + lane] = aggs[((size_t)t*17 + k)*BN + node];
    }
    __syncthreads();

    // ---- P1: GraphConv octet -> ct conv region ----
    const int j0 = w*8;
    {
        float c[8];
        #pragma unroll
        for (int j=0;j<8;j++) c[j] = b_rel[j0+j];
        #pragma unroll
        for (int k=0;k<GCIN;k++){
            const float av = ag[k*PADA + lane];
            const float xv = ctl[k];
            const float* wr = W_rel  + k*HID + j0;
            const float* wo = W_root + k*HID + j0;
            #pragma unroll
            for (int j=0;j<8;j++) c[j] += av*wr[j] + xv*wo[j];
        }
        #pragma unroll
        for (int j=0;j<8;j++) ctl[18+j0+j] = sigf(c[j]);
    }
    __syncthreads();

    // ---- P2: GRU, 8 outputs/wave, 4 accumulators, inputs from LDS ----
    float xacc = 0.f;
    #pragma unroll 1
    for (int j=0;j<8;j++){
        const int jj = j0 + j;
        const float* wr = Wih + (size_t) jj      *82;
        const float* wz = Wih + (size_t)(jj+ 64) *82;
        const float* wn = Wih + (size_t)(jj+128) *82;
        float accr = bih[jj]     + bhh[jj];
        float accz = bih[64+jj]  + bhh[64+jj];
        float accin = bih[128+jj];
        float acchn = bhh[128+jj];
        #pragma unroll
        for (int k=0;k<82;k++){
            const float xv = ctl[k];
            accr += xv*wr[k]; accz += xv*wz[k]; accin += xv*wn[k];
        }
        const float* vr = Whh + (size_t) jj      *HID;
        const float* vz = Whh + (size_t)(jj+ 64) *HID;
        const float* vn = Whh + (size_t)(jj+128) *HID;
        #pragma unroll
        for (int k=0;k<HID;k++){
            const float hv = ctl[82+k];
            accr += hv*vr[k]; accz += hv*vz[k]; acchn += hv*vn[k];
        }
        const float r = sigf(accr);
        const float z = sigf(accz);
        const float n = tanhf_(accin + r*acchn);
        const float hold = ctl[82+jj];
        const float hp = (1.f - z)*n + z*hold;
        h_out[(size_t)jj*BN + node] = hp;
        xacc += hp * Wout[jj];
    }

    xs[w][lane] = xacc;
    __syncthreads();
    if (w == 0){
        float v = bout[0];
        #pragma unroll
        for (int q=0;q<8;q++) v += xs[q][lane];
        xn_out[node] = v;
    }
}

// ---------------- decoder step ----------------
__global__ __launch_bounds__(512, 4) void dec_step(
    const float* __restrict__ X,
    const float* __restrict__ Win, const float* __restrict__ bin,
    const float* __restrict__ Wih, const float* __restrict__ Whh,
    const float* __restrict__ bih, const float* __restrict__ bhh,
    const float* __restrict__ Wout, const float* __restrict__ bout,
    const float* __restrict__ h_in, float* __restrict__ h_out,
    const float* __restrict__ xn_in, float* __restrict__ xn_out,
    float* __restrict__ out, int t)
{
    __shared__ float ct[64*PADD];    // [lane][0:64)=xin, [64:128)=h
    __shared__ float xs[8][64];

    const int lane = threadIdx.x & 63;
    int w = threadIdx.x >> 6;
    w = __builtin_amdgcn_readfirstlane(w);
    const int node = blockIdx.x*64 + lane;
    const int b    = node / NN;
    const int nloc = node - b*NN;
    float* ctl = ct + lane*PADD;

    const float* Xt = X + (size_t)(b*TT + HIST + t)*NN*FF;

    // stage h (all waves) + xin octet (each wave computes its 8)
    #pragma unroll
    for (int i=0;i<8;i++){
        const int k = w*8 + i;
        ctl[64+k] = h_in[(size_t)k*BN + node];
    }
    const int j0 = w*8;
    {
        float x0 = xn_in[node];
        float x1 = Xt[nloc*FF + 13];
        float x2 = Xt[nloc*FF + 14];
        float x3 = Xt[nloc*FF + 15];
        #pragma unroll
        for (int j=0;j<8;j++){
            const int k = j0 + j;
            ctl[k] = bin[k] + x0*Win[k] + x1*Win[64+k] + x2*Win[128+k] + x3*Win[192+k];
        }
    }
    __syncthreads();

    float xacc = 0.f;
    #pragma unroll 1
    for (int j=0;j<8;j++){
        const int jj = j0 + j;
        const float* wr = Wih + (size_t) jj      *HID;
        const float* wz = Wih + (size_t)(jj+ 64) *HID;
        const float* wn = Wih + (size_t)(jj+128) *HID;
        float accr = bih[jj]     + bhh[jj];
        float accz = bih[64+jj]  + bhh[64+jj];
        float accin = bih[128+jj];
        float acchn = bhh[128+jj];
        #pragma unroll
        for (int k=0;k<HID;k++){
            const float xv = ctl[k];
            accr += xv*wr[k]; accz += xv*wz[k]; accin += xv*wn[k];
        }
        const float* vr = Whh + (size_t) jj      *HID;
        const float* vz = Whh + (size_t)(jj+ 64) *HID;
        const float* vn = Whh + (size_t)(jj+128) *HID;
        #pragma unroll
        for (int k=0;k<HID;k++){
            const float hv = ctl[64+k];
            accr += hv*vr[k]; accz += hv*vz[k]; acchn += hv*vn[k];
        }
        const float r = sigf(accr);
        const float z = sigf(accz);
        const float n = tanhf_(accin + r*acchn);
        const float hold = ctl[64+jj];
        const float hp = (1.f - z)*n + z*hold;
        h_out[(size_t)jj*BN + node] = hp;
        xacc += hp * Wout[jj];
    }

    xs[w][lane] = xacc;
    __syncthreads();
    if (w == 0){
        float v = bout[0];
        #pragma unroll
        for (int q=0;q<8;q++) v += xs[q][lane];
        xn_out[node] = v;
        out[(size_t)(b*FC + t)*NN + nloc] = v;
    }
}

extern "C" void kernel_launch(void* const* d_in, const int* in_sizes, int n_in,
                              void* d_out, int out_size, void* d_ws, size_t ws_size,
                              hipStream_t stream)
{
    const float* X     = (const float*)d_in[0];
    const float* y     = (const float*)d_in[1];
    const int*   ei    = (const int*)  d_in[2];   // [2][E]; row 0 = src
    const float* ew    = (const float*)d_in[3];
    const float* W_rel = (const float*)d_in[4];
    const float* b_rel = (const float*)d_in[5];
    const float* W_root= (const float*)d_in[6];
    const float* eWih  = (const float*)d_in[7];
    const float* eWhh  = (const float*)d_in[8];
    const float* ebih  = (const float*)d_in[9];
    const float* ebhh  = (const float*)d_in[10];
    const float* eWout = (const float*)d_in[11];
    const float* ebout = (const float*)d_in[12];
    const float* dWin  = (const float*)d_in[13];
    const float* dbin  = (const float*)d_in[14];
    const float* dWih  = (const float*)d_in[15];
    const float* dWhh  = (const float*)d_in[16];
    const float* dbih  = (const float*)d_in[17];
    const float* dbhh  = (const float*)d_in[18];
    const float* dWout = (const float*)d_in[19];
    const float* dbout = (const float*)d_in[20];
    float* out = (float*)d_out;

    // workspace: static agg (24*17*BN = 52.2MB) + ping-pong h (2x8.19MB) + xn (2x128KB)
    float* aggs = (float*)d_ws;
    float* h0 = aggs + (size_t)24*17*BN;
    float* h1 = h0 + (size_t)BN*HID;
    float* x0 = h1 + (size_t)BN*HID;
    float* x1 = x0 + BN;

    hipMemsetAsync(h0, 0, (size_t)BN*HID*sizeof(float), stream);
    hipMemsetAsync(x0, 0, (size_t)BN*sizeof(float), stream);

    const int* esrc = ei;  // first E entries

    // hoisted static-feature aggregation (LDS-staged, one block per (b,t))
    const int smem = (NN*FF + NN)*sizeof(float);   // 68 KB > 64 KB static limit
    static bool attr_set = false;
    hipFuncSetAttribute((const void*)agg_pre,
                        hipFuncAttributeMaxDynamicSharedMemorySize, smem);
    (void)attr_set;
    agg_pre<<<dim3(BX,24), 1024, smem, stream>>>(X, y, esrc, ew, aggs);

    float* hin = h0; float* hout = h1;
    float* xin = x0; float* xout = x1;

    for (int t=0; t<HIST; t++){
        enc_step<<<500, 512, 0, stream>>>(X, y, esrc, ew, aggs, W_rel, b_rel, W_root,
                                          eWih, eWhh, ebih, ebhh, eWout, ebout,
                                          hin, hout, xin, xout, t);
        float* tmp;
        tmp = hin; hin = hout; hout = tmp;
        tmp = xin; xin = xout; xout = tmp;
    }
    for (int t=0; t<FC; t++){
        dec_step<<<500, 512, 0, stream>>>(X, dWin, dbin, dWih, dWhh, dbih, dbhh,
                                          dWout, dbout, hin, hout, xin, xout, out, t);
        float* tmp;
        tmp = hin; hin = hout; hout = tmp;
        tmp = xin; xin = xout; xout = tmp;
    }
}

// Round 7
// 2693.542 us; speedup vs baseline: 6.1927x; 6.1927x over previous
//
#include <hip/hip_runtime.h>
#include <cstdint>

#define BX   32
#define NN   1000
#define FF   16
#define TT   48          // HIST + FC
#define HIST 24
#define FC   24
#define HID  64
#define DEG  16
#define GCIN 18          // F + 2
#define BN   (BX*NN)     // 32000 nodes

__device__ __forceinline__ float sigf(float x)  { return 1.0f/(1.0f+__expf(-x)); }
__device__ __forceinline__ float tanhf_(float x){ return 2.0f/(1.0f+__expf(-2.0f*x)) - 1.0f; }

// ---------------- pre-pass: static part of the edge aggregation ----------------
// One block per (b,t); X[b][t] slice (64KB) + y (4KB) staged in dynamic LDS, so
// the 16-edge scatter hits LDS instead of HBM/L2. HBM = read-once + write-once.
__global__ __launch_bounds__(1024, 4) void agg_pre(
    const float* __restrict__ X, const float* __restrict__ y,
    const int*   __restrict__ esrc, const float* __restrict__ ew,
    float* __restrict__ aggs)
{
    extern __shared__ float sm[];
    float* Xs = sm;            // [1000][16]
    float* ys = sm + NN*FF;    // [1000]

    const int b = blockIdx.x;  // 0..31
    const int t = blockIdx.y;  // 0..23
    const float* Xt = X + (size_t)(b*TT + t)*NN*FF;
    const float* yt = y + (size_t)(b*TT + t)*NN;

    for (int i = threadIdx.x; i < NN*FF/4; i += 1024)
        ((float4*)Xs)[i] = ((const float4*)Xt)[i];
    for (int i = threadIdx.x; i < NN; i += 1024)
        ys[i] = yt[i];
    __syncthreads();

    const int nl = threadIdx.x;
    if (nl < NN){
        const int node = b*NN + nl;
        float agg[17];
        #pragma unroll
        for (int i=0;i<17;i++) agg[i]=0.f;

        const int e0 = node*DEG;
        const int4*   sv = (const int4*)  (esrc + e0);
        const float4* wv = (const float4*)(ew   + e0);
        #pragma unroll
        for (int q=0;q<4;q++){
            int4   s4 = sv[q];
            float4 w4 = wv[q];
            const int   ss[4] = {s4.x, s4.y, s4.z, s4.w};
            const float ww[4] = {w4.x, w4.y, w4.z, w4.w};
            #pragma unroll
            for (int i=0;i<4;i++){
                const int sl = ss[i] - b*NN;
                const float wgt = ww[i];
                agg[0] += wgt * ys[sl];
                const float4* sr = (const float4*)&Xs[sl*FF];
                #pragma unroll
                for (int q2=0;q2<4;q2++){
                    float4 v = sr[q2];
                    agg[1+4*q2] += wgt*v.x; agg[2+4*q2] += wgt*v.y;
                    agg[3+4*q2] += wgt*v.z; agg[4+4*q2] += wgt*v.w;
                }
            }
        }
        #pragma unroll
        for (int k=0;k<17;k++) aggs[((size_t)t*17 + k)*BN + node] = agg[k];
    }
}

// ---------------- encoder step (R3-exact: measured 2911us total) --------------
// block = 256 threads = 4 waves; 64 nodes/block (lane = node), wave = j-quarter
// (16 of 64 hidden outputs). grid = 500 -> 2000 waves (~2 waves/SIMD).
__global__ __launch_bounds__(256, 2) void enc_step(
    const float* __restrict__ X, const float* __restrict__ y,
    const int*   __restrict__ esrc, const float* __restrict__ ew,
    const float* __restrict__ aggs,
    const float* __restrict__ W_rel, const float* __restrict__ b_rel,
    const float* __restrict__ W_root,
    const float* __restrict__ Wih, const float* __restrict__ Whh,
    const float* __restrict__ bih, const float* __restrict__ bhh,
    const float* __restrict__ Wout, const float* __restrict__ bout,
    const float* __restrict__ h_in, float* __restrict__ h_out,
    const float* __restrict__ xn_in, float* __restrict__ xn_out,
    int t)
{
    __shared__ float cl[HID][64];    // conv exchange (stride-1 in node: conflict-free)
    __shared__ float xs[4][64];      // xn partial sums

    const int lane = threadIdx.x & 63;
    int jq = threadIdx.x >> 6;                  // 0..3 j-quarter
    jq = __builtin_amdgcn_readfirstlane(jq);    // wave-uniform -> s_load weights
    const int node = blockIdx.x*64 + lane;      // < 32000
    const int b    = node / NN;
    const int nloc = node - b*NN;

    const float* Xt = X + (size_t)(b*TT + t)*NN*FF;
    const float* yt = y + (size_t)(b*TT + t)*NN;

    // ---- own features xg = [xn, y, X] ----
    float xg[GCIN];
    xg[0] = xn_in[node];
    xg[1] = yt[nloc];
    {
        const float4* xr = (const float4*)(Xt + nloc*FF);
        #pragma unroll
        for (int q=0;q<4;q++){ float4 v = xr[q];
            xg[2+4*q]=v.x; xg[3+4*q]=v.y; xg[4+4*q]=v.z; xg[5+4*q]=v.w; }
    }

    // ---- aggregation: dynamic xn channel gathered, static channels loaded ----
    float agf[GCIN];
    {
        float a0 = 0.f;
        const int e0 = node*DEG;
        const int4*   sv = (const int4*)  (esrc + e0);
        const float4* wv = (const float4*)(ew   + e0);
        #pragma unroll
        for (int q=0;q<4;q++){
            int4   s4 = sv[q];
            float4 w4 = wv[q];
            a0 += w4.x * xn_in[s4.x];
            a0 += w4.y * xn_in[s4.y];
            a0 += w4.z * xn_in[s4.z];
            a0 += w4.w * xn_in[s4.w];
        }
        agf[0] = a0;
    }
    #pragma unroll
    for (int k=0;k<17;k++) agf[1+k] = aggs[((size_t)t*17 + k)*BN + node];

    // ---- GraphConv quarter (16 outputs per wave) -> LDS ----
    const int j0 = jq*16;
    {
        float c[16];
        #pragma unroll
        for (int j=0;j<16;j++) c[j] = b_rel[j0+j];
        #pragma unroll
        for (int k=0;k<GCIN;k++){
            const float* wr = W_rel  + k*HID + j0;
            const float* wo = W_root + k*HID + j0;
            #pragma unroll
            for (int j=0;j<16;j++) c[j] += agf[k]*wr[j] + xg[k]*wo[j];
        }
        #pragma unroll
        for (int j=0;j<16;j++) cl[j0+j][lane] = sigf(c[j]);
    }
    __syncthreads();

    float conv[HID];
    #pragma unroll
    for (int k=0;k<HID;k++) conv[k] = cl[k][lane];

    float h[HID];
    #pragma unroll
    for (int k=0;k<HID;k++) h[k] = h_in[(size_t)k*BN + node];

    // ---- GRU gates, 16 outputs per wave (dynamic j-loop, static inner dots) ----
    float xacc = 0.f;
    for (int j=0;j<16;j++){
        const int jj = j0 + j;
        const float* wr_r = Wih + (size_t) jj      *82;
        const float* wr_z = Wih + (size_t)(jj+ 64) *82;
        const float* wr_n = Wih + (size_t)(jj+128) *82;
        float ir = bih[jj], iz = bih[64+jj], in2 = bih[128+jj];
        #pragma unroll
        for (int k=0;k<GCIN;k++){
            const float xv = xg[k];
            ir += xv*wr_r[k]; iz += xv*wr_z[k]; in2 += xv*wr_n[k];
        }
        #pragma unroll
        for (int k=0;k<HID;k++){
            const float xv = conv[k];
            ir += xv*wr_r[GCIN+k]; iz += xv*wr_z[GCIN+k]; in2 += xv*wr_n[GCIN+k];
        }
        const float* wh_r = Whh + (size_t) jj      *HID;
        const float* wh_z = Whh + (size_t)(jj+ 64) *HID;
        const float* wh_n = Whh + (size_t)(jj+128) *HID;
        float hr = bhh[jj], hz = bhh[64+jj], hn2 = bhh[128+jj];
        #pragma unroll
        for (int k=0;k<HID;k++){
            const float hv = h[k];
            hr += hv*wh_r[k]; hz += hv*wh_z[k]; hn2 += hv*wh_n[k];
        }
        const float r = sigf(ir+hr);
        const float z = sigf(iz+hz);
        const float n = tanhf_(in2 + r*hn2);
        const float hold = h_in[(size_t)jj*BN + node];   // == h[jj] (L1 hit; avoids scratch)
        const float hp = (1.f - z)*n + z*hold;
        h_out[(size_t)jj*BN + node] = hp;
        xacc += hp * Wout[jj];
    }

    xs[jq][lane] = xacc;
    __syncthreads();
    if (jq == 0)
        xn_out[node] = xs[0][lane] + xs[1][lane] + xs[2][lane] + xs[3][lane] + bout[0];
}

// ---------------- decoder step (R3-exact) ----------------
__global__ __launch_bounds__(256, 2) void dec_step(
    const float* __restrict__ X,
    const float* __restrict__ Win, const float* __restrict__ bin,
    const float* __restrict__ Wih, const float* __restrict__ Whh,
    const float* __restrict__ bih, const float* __restrict__ bhh,
    const float* __restrict__ Wout, const float* __restrict__ bout,
    const float* __restrict__ h_in, float* __restrict__ h_out,
    const float* __restrict__ xn_in, float* __restrict__ xn_out,
    float* __restrict__ out, int t)
{
    __shared__ float xs[4][64];

    const int lane = threadIdx.x & 63;
    int jq = threadIdx.x >> 6;
    jq = __builtin_amdgcn_readfirstlane(jq);
    const int node = blockIdx.x*64 + lane;
    const int b    = node / NN;
    const int nloc = node - b*NN;

    const float* Xt = X + (size_t)(b*TT + HIST + t)*NN*FF;

    float x4[4];
    x4[0] = xn_in[node];
    x4[1] = Xt[nloc*FF + 13];
    x4[2] = Xt[nloc*FF + 14];
    x4[3] = Xt[nloc*FF + 15];

    // xin = x4 @ Win(4x64) + bin  (computed fully by each wave; cheap)
    float xin[HID];
    #pragma unroll
    for (int j=0;j<HID;j++)
        xin[j] = bin[j] + x4[0]*Win[j] + x4[1]*Win[64+j] + x4[2]*Win[128+j] + x4[3]*Win[192+j];

    float h[HID];
    #pragma unroll
    for (int k=0;k<HID;k++) h[k] = h_in[(size_t)k*BN + node];

    const int j0 = jq*16;
    float xacc = 0.f;
    for (int j=0;j<16;j++){
        const int jj = j0 + j;
        const float* wr_r = Wih + (size_t) jj      *HID;
        const float* wr_z = Wih + (size_t)(jj+ 64) *HID;
        const float* wr_n = Wih + (size_t)(jj+128) *HID;
        float ir = bih[jj], iz = bih[64+jj], in2 = bih[128+jj];
        #pragma unroll
        for (int k=0;k<HID;k++){
            const float xv = xin[k];
            ir += xv*wr_r[k]; iz += xv*wr_z[k]; in2 += xv*wr_n[k];
        }
        const float* wh_r = Whh + (size_t) jj      *HID;
        const float* wh_z = Whh + (size_t)(jj+ 64) *HID;
        const float* wh_n = Whh + (size_t)(jj+128) *HID;
        float hr = bhh[jj], hz = bhh[64+jj], hn2 = bhh[128+jj];
        #pragma unroll
        for (int k=0;k<HID;k++){
            const float hv = h[k];
            hr += hv*wh_r[k]; hz += hv*wh_z[k]; hn2 += hv*wh_n[k];
        }
        const float r = sigf(ir+hr);
        const float z = sigf(iz+hz);
        const float n = tanhf_(in2 + r*hn2);
        const float hold = h_in[(size_t)jj*BN + node];
        const float hp = (1.f - z)*n + z*hold;
        h_out[(size_t)jj*BN + node] = hp;
        xacc += hp * Wout[jj];
    }

    xs[jq][lane] = xacc;
    __syncthreads();
    if (jq == 0){
        const float v = xs[0][lane] + xs[1][lane] + xs[2][lane] + xs[3][lane] + bout[0];
        xn_out[node] = v;
        out[(size_t)(b*FC + t)*NN + nloc] = v;
    }
}

extern "C" void kernel_launch(void* const* d_in, const int* in_sizes, int n_in,
                              void* d_out, int out_size, void* d_ws, size_t ws_size,
                              hipStream_t stream)
{
    const float* X     = (const float*)d_in[0];
    const float* y     = (const float*)d_in[1];
    const int*   ei    = (const int*)  d_in[2];   // [2][E]; row 0 = src
    const float* ew    = (const float*)d_in[3];
    const float* W_rel = (const float*)d_in[4];
    const float* b_rel = (const float*)d_in[5];
    const float* W_root= (const float*)d_in[6];
    const float* eWih  = (const float*)d_in[7];
    const float* eWhh  = (const float*)d_in[8];
    const float* ebih  = (const float*)d_in[9];
    const float* ebhh  = (const float*)d_in[10];
    const float* eWout = (const float*)d_in[11];
    const float* ebout = (const float*)d_in[12];
    const float* dWin  = (const float*)d_in[13];
    const float* dbin  = (const float*)d_in[14];
    const float* dWih  = (const float*)d_in[15];
    const float* dWhh  = (const float*)d_in[16];
    const float* dbih  = (const float*)d_in[17];
    const float* dbhh  = (const float*)d_in[18];
    const float* dWout = (const float*)d_in[19];
    const float* dbout = (const float*)d_in[20];
    float* out = (float*)d_out;

    // workspace: static agg (24*17*BN = 52.2MB) + ping-pong h (2x8.19MB) + xn (2x128KB)
    float* aggs = (float*)d_ws;
    float* h0 = aggs + (size_t)24*17*BN;
    float* h1 = h0 + (size_t)BN*HID;
    float* x0 = h1 + (size_t)BN*HID;
    float* x1 = x0 + BN;

    hipMemsetAsync(h0, 0, (size_t)BN*HID*sizeof(float), stream);
    hipMemsetAsync(x0, 0, (size_t)BN*sizeof(float), stream);

    const int* esrc = ei;  // first E entries

    // hoisted static-feature aggregation (LDS-staged, one block per (b,t))
    const int smem = (NN*FF + NN)*sizeof(float);   // 68 KB > 64 KB static limit
    hipFuncSetAttribute((const void*)agg_pre,
                        hipFuncAttributeMaxDynamicSharedMemorySize, smem);
    agg_pre<<<dim3(BX,24), 1024, smem, stream>>>(X, y, esrc, ew, aggs);

    float* hin = h0; float* hout = h1;
    float* xin = x0; float* xout = x1;

    for (int t=0; t<HIST; t++){
        enc_step<<<500, 256, 0, stream>>>(X, y, esrc, ew, aggs, W_rel, b_rel, W_root,
                                          eWih, eWhh, ebih, ebhh, eWout, ebout,
                                          hin, hout, xin, xout, t);
        float* tmp;
        tmp = hin; hin = hout; hout = tmp;
        tmp = xin; xin = xout; xout = tmp;
    }
    for (int t=0; t<FC; t++){
        dec_step<<<500, 256, 0, stream>>>(X, dWin, dbin, dWih, dWhh, dbih, dbhh,
                                          dWout, dbout, hin, hout, xin, xout, out, t);
        float* tmp;
        tmp = hin; hin = hout; hout = tmp;
        tmp = xin; xin = xout; xout = tmp;
    }
}

// Round 8
// 707.980 us; speedup vs baseline: 23.5603x; 3.8045x over previous
//
#include <hip/hip_runtime.h>
#include <cstdint>

#define BX   32
#define NN   1000
#define FF   16
#define TT   48          // HIST + FC
#define HIST 24
#define FC   24
#define HID  64
#define DEG  16
#define BN   (BX*NN)     // 32000 nodes

typedef __attribute__((ext_vector_type(8)))  short s8v;   // bf16x8 MFMA frag (4 VGPR)
typedef __attribute__((ext_vector_type(16))) float f16v;  // 32x32 accumulator

__device__ __forceinline__ float sigf(float x)  { return 1.0f/(1.0f+__expf(-x)); }
__device__ __forceinline__ float tanhf_(float x){ return 2.0f/(1.0f+__expf(-2.0f*x)) - 1.0f; }
__device__ __forceinline__ unsigned short f2bf(float x){
    unsigned int u = __float_as_uint(x);
    return (unsigned short)((u + 0x7FFFu + ((u>>16)&1u)) >> 16);   // RNE
}
__device__ __forceinline__ float bf2f(unsigned short b){
    return __uint_as_float(((unsigned int)b)<<16);
}

// ---------------- one-time: bf16 weight images in LDS-exact layout ----------------
// encB: [B1 64x72 | Bih 192x104 | Bhh 192x72]  (bf16 units; pitches 16B-multiples)
// decB: [Bihd 192x72 | Bhhd 192x72]
__global__ void prep_weights(
    const float* __restrict__ W_rel, const float* __restrict__ W_root,
    const float* __restrict__ eWih, const float* __restrict__ eWhh,
    const float* __restrict__ dWih, const float* __restrict__ dWhh,
    unsigned short* __restrict__ encB, unsigned short* __restrict__ decB)
{
    const int i = blockIdx.x*256 + threadIdx.x;   // grid covers 192*104 = 19968
    if (i < 64*72){                                // B1[n][k]: k<18 W_rel, 32..49 W_root
        int n = i/72, k = i%72;
        float v = 0.f;
        if (k < 18) v = W_rel[k*64 + n];
        else if (k >= 32 && k < 50) v = W_root[(k-32)*64 + n];
        encB[i] = f2bf(v);
    }
    if (i < 192*104){                              // Bih[n][k]: k<18 xg-part, 32..95 conv-part
        int n = i/104, k = i%104;
        float v = 0.f;
        if (k < 18) v = eWih[n*82 + k];
        else if (k >= 32 && k < 96) v = eWih[n*82 + 18 + (k-32)];
        encB[4608 + i] = f2bf(v);
    }
    if (i < 192*72){                               // Bhh / dec images
        int n = i/72, k = i%72;
        encB[24576 + i] = f2bf((k < 64) ? eWhh[n*64 + k] : 0.f);
        decB[i]         = f2bf((k < 64) ? dWih[n*64 + k] : 0.f);
        decB[13824 + i] = f2bf((k < 64) ? dWhh[n*64 + k] : 0.f);
    }
}

// ---------------- pre-pass: static edge aggregation (R7-proven) ----------------
__global__ __launch_bounds__(1024, 4) void agg_pre(
    const float* __restrict__ X, const float* __restrict__ y,
    const int*   __restrict__ esrc, const float* __restrict__ ew,
    float* __restrict__ aggs)
{
    extern __shared__ float sm[];
    float* Xs = sm;            // [1000][16]
    float* ys = sm + NN*FF;    // [1000]

    const int b = blockIdx.x;
    const int t = blockIdx.y;
    const float* Xt = X + (size_t)(b*TT + t)*NN*FF;
    const float* yt = y + (size_t)(b*TT + t)*NN;

    for (int i = threadIdx.x; i < NN*FF/4; i += 1024)
        ((float4*)Xs)[i] = ((const float4*)Xt)[i];
    for (int i = threadIdx.x; i < NN; i += 1024)
        ys[i] = yt[i];
    __syncthreads();

    const int nl = threadIdx.x;
    if (nl < NN){
        const int node = b*NN + nl;
        float agg[17];
        #pragma unroll
        for (int i=0;i<17;i++) agg[i]=0.f;
        const int4*   sv = (const int4*)  (esrc + node*DEG);
        const float4* wv = (const float4*)(ew   + node*DEG);
        #pragma unroll
        for (int q=0;q<4;q++){
            int4 s4 = sv[q]; float4 w4 = wv[q];
            const int   ss[4] = {s4.x, s4.y, s4.z, s4.w};
            const float ww[4] = {w4.x, w4.y, w4.z, w4.w};
            #pragma unroll
            for (int i=0;i<4;i++){
                const int sl = ss[i] - b*NN;
                const float wgt = ww[i];
                agg[0] += wgt * ys[sl];
                const float4* sr = (const float4*)&Xs[sl*FF];
                #pragma unroll
                for (int q2=0;q2<4;q2++){
                    float4 v = sr[q2];
                    agg[1+4*q2] += wgt*v.x; agg[2+4*q2] += wgt*v.y;
                    agg[3+4*q2] += wgt*v.z; agg[4+4*q2] += wgt*v.w;
                }
            }
        }
        #pragma unroll
        for (int k=0;k<17;k++) aggs[((size_t)t*17 + k)*BN + node] = agg[k];
    }
}

// ---------------- encoder step: MFMA bf16 ----------------
// 128 nodes/block, 8 waves (wave = (mt = w>>1, jt = w&1)), grid 250.
// LDS (bf16 units): B1@0(64x72) Bih@4608(192x104) Bhh@24576(192x72)
//                   A_s@38400(128x136) = [agg18|0|xg18|0|conv64|pad]
//                   A_h@55808(128x136) = [h_hi64|h_lo64|pad]
#define E_OFFB1  0
#define E_OFFBIH 4608
#define E_OFFBHH 24576
#define E_OFFAS  38400
#define E_OFFAH  55808
#define E_SMEM   146432
#define PAS  136
#define PBIH 104
#define PB72 72

__global__ __launch_bounds__(512, 2) void enc_step(
    const float* __restrict__ X, const float* __restrict__ y,
    const int* __restrict__ esrc, const float* __restrict__ ew,
    const float* __restrict__ aggs, const unsigned short* __restrict__ encB,
    const float* __restrict__ b_rel, const float* __restrict__ bih,
    const float* __restrict__ bhh, const float* __restrict__ Wout,
    const float* __restrict__ bout,
    const float* __restrict__ h_in, float* __restrict__ h_out,
    const float* __restrict__ xn_in, float* __restrict__ xn_out, int t)
{
    extern __shared__ char smraw[];
    unsigned short* sm16 = (unsigned short*)smraw;
    const int tid  = threadIdx.x;
    const int lane = tid & 63;
    const int w    = __builtin_amdgcn_readfirstlane(tid >> 6);
    const int mt = w >> 1, jt = w & 1;
    const int blk = blockIdx.x;

    // ---- P0a: B image -> LDS (linear 76800B memcpy) ----
    {
        const uint4* src = (const uint4*)encB;
        uint4* dst = (uint4*)smraw;
        for (int i = tid; i < 4800; i += 512) dst[i] = src[i];
    }
    // ---- P0b: zero A_s gap cols 18..31, 50..63 ----
    {
        unsigned int* as32 = (unsigned int*)(sm16 + E_OFFAS);
        for (int i = tid; i < 128*14; i += 512){
            int node = i & 127, q = i >> 7;
            int col = (q < 7) ? (18 + 2*q) : (50 + 2*(q-7));
            as32[(node*PAS + col) >> 1] = 0u;
        }
    }
    // ---- P0c: static agg channels -> A_s cols 1..17 ----
    for (int i = tid; i < 128*17; i += 512){
        int node = i & 127, k = i >> 7;
        float v = aggs[((size_t)t*17 + k)*BN + blk*128 + node];
        sm16[E_OFFAS + node*PAS + 1 + k] = f2bf(v);
    }
    // ---- P0e: h -> A_h as [hi|lo] bf16 (coalesced reads, packed u32 writes) ----
    {
        const int node = tid >> 2, c0 = (tid & 3)*16;
        const float4* hp4 = (const float4*)(h_in + (size_t)(blk*128 + node)*64 + c0);
        unsigned int* ah32 = (unsigned int*)(sm16 + E_OFFAH);
        #pragma unroll
        for (int qq = 0; qq < 4; qq++){
            float4 v = hp4[qq];
            float vs[4] = {v.x, v.y, v.z, v.w};
            #pragma unroll
            for (int pp = 0; pp < 2; pp++){
                unsigned short h0 = f2bf(vs[2*pp]),   h1 = f2bf(vs[2*pp+1]);
                unsigned short l0 = f2bf(vs[2*pp]   - bf2f(h0));
                unsigned short l1 = f2bf(vs[2*pp+1] - bf2f(h1));
                int col = c0 + 4*qq + 2*pp;
                ah32[(node*PAS + col)      >> 1] = (unsigned int)h0 | ((unsigned int)h1 << 16);
                ah32[(node*PAS + 64 + col) >> 1] = (unsigned int)l0 | ((unsigned int)l1 << 16);
            }
        }
    }
    // ---- P0d: xn-gather (col0) + xg (cols 32..49), threads 0..127 ----
    if (tid < 128){
        const int node = tid, node_g = blk*128 + node;
        const int b = node_g / NN, nloc = node_g - b*NN;
        const float* Xt = X + (size_t)(b*TT + t)*NN*FF;
        const float* yt = y + (size_t)(b*TT + t)*NN;
        unsigned short* as = sm16 + E_OFFAS + node*PAS;
        float a0 = 0.f;
        const int4*   sv = (const int4*)  (esrc + node_g*DEG);
        const float4* wv = (const float4*)(ew   + node_g*DEG);
        #pragma unroll
        for (int q=0;q<4;q++){
            int4 s4 = sv[q]; float4 w4 = wv[q];
            a0 += w4.x*xn_in[s4.x] + w4.y*xn_in[s4.y]
                + w4.z*xn_in[s4.z] + w4.w*xn_in[s4.w];
        }
        as[0]  = f2bf(a0);
        as[32] = f2bf(xn_in[node_g]);
        as[33] = f2bf(yt[nloc]);
        const float4* xr = (const float4*)(Xt + nloc*FF);
        #pragma unroll
        for (int q=0;q<4;q++){
            float4 v = xr[q];
            as[34+4*q] = f2bf(v.x); as[35+4*q] = f2bf(v.y);
            as[36+4*q] = f2bf(v.z); as[37+4*q] = f2bf(v.w);
        }
    }
    __syncthreads();

    // ---- P1: GraphConv GEMM (A_s k-window [0,64)) -> sigmoid -> A_s cols 64..127 ----
    {
        f16v acc = {};
        const int rA = mt*32 + (lane & 31);
        const int rB = jt*32 + (lane & 31);
        const int ke = (lane >> 5)*8;
        #pragma unroll
        for (int ks=0; ks<4; ks++){
            s8v a = *(const s8v*)(sm16 + E_OFFAS + rA*PAS  + ks*16 + ke);
            s8v b = *(const s8v*)(sm16 + E_OFFB1 + rB*PB72 + ks*16 + ke);
            acc = __builtin_amdgcn_mfma_f32_32x32x16_bf16(a, b, acc, 0, 0, 0);
        }
        const int j = jt*32 + (lane & 31);
        const float brl = b_rel[j];
        #pragma unroll
        for (int reg=0; reg<16; reg++){
            int row = (reg&3) + 8*(reg>>2) + 4*(lane>>5);
            sm16[E_OFFAS + (mt*32 + row)*PAS + 64 + j] = f2bf(sigf(acc[reg] + brl));
        }
    }
    __syncthreads();

    // ---- P2: GRU GEMMs ----
    f16v accx[3] = {{},{},{}};
    f16v acch[3] = {{},{},{}};
    {
        const int rA = mt*32 + (lane & 31);
        const int ln = lane & 31;
        const int ke = (lane >> 5)*8;
        #pragma unroll
        for (int ks=0; ks<6; ks++){               // x-GEMM: window [32,128), K=96
            s8v a = *(const s8v*)(sm16 + E_OFFAS + rA*PAS + 32 + ks*16 + ke);
            #pragma unroll
            for (int nt=0; nt<3; nt++){
                int NT = jt + nt*2;
                s8v b = *(const s8v*)(sm16 + E_OFFBIH + (NT*32 + ln)*PBIH + ks*16 + ke);
                accx[nt] = __builtin_amdgcn_mfma_f32_32x32x16_bf16(a, b, accx[nt], 0,0,0);
            }
        }
        #pragma unroll
        for (int ks=0; ks<4; ks++){               // h-GEMM: hi + lo passes, K=64 each
            s8v ah = *(const s8v*)(sm16 + E_OFFAH + rA*PAS      + ks*16 + ke);
            s8v al = *(const s8v*)(sm16 + E_OFFAH + rA*PAS + 64 + ks*16 + ke);
            #pragma unroll
            for (int nt=0; nt<3; nt++){
                int NT = jt + nt*2;
                s8v b = *(const s8v*)(sm16 + E_OFFBHH + (NT*32 + ln)*PB72 + ks*16 + ke);
                acch[nt] = __builtin_amdgcn_mfma_f32_32x32x16_bf16(ah, b, acch[nt], 0,0,0);
                acch[nt] = __builtin_amdgcn_mfma_f32_32x32x16_bf16(al, b, acch[nt], 0,0,0);
            }
        }
    }
    __syncthreads();                              // A_h reads done before hL overwrite

    // ---- P3: GRU epilogue (fp32), h' -> global + LDS ----
    {
        const int j = jt*32 + (lane & 31);
        const float br  = bih[j]     + bhh[j];
        const float bz  = bih[64+j]  + bhh[64+j];
        const float bin_ = bih[128+j];
        const float bhn  = bhh[128+j];
        float* hL = (float*)(smraw + E_OFFAH*2);  // reuse A_h region, pitch 68 f32
        #pragma unroll
        for (int reg=0; reg<16; reg++){
            int row = (reg&3) + 8*(reg>>2) + 4*(lane>>5);
            int node_l = mt*32 + row;
            size_t gidx = (size_t)(blk*128 + node_l)*64 + j;
            float r  = sigf(accx[0][reg] + acch[0][reg] + br);
            float z  = sigf(accx[1][reg] + acch[1][reg] + bz);
            float nn = tanhf_(accx[2][reg] + bin_ + r*(acch[2][reg] + bhn));
            float hp = (1.f - z)*nn + z*h_in[gidx];
            h_out[gidx] = hp;
            hL[node_l*68 + j] = hp;
        }
    }
    __syncthreads();

    // ---- P4: xn = h' @ Wout + bout ----
    {
        const float* hL = (const float*)(smraw + E_OFFAH*2);
        float* xs = (float*)smraw;                // reuse B1 region
        const int node_l = tid >> 2, q = tid & 3;
        float s = 0.f;
        #pragma unroll
        for (int i=0;i<16;i++) s += hL[node_l*68 + q*16 + i] * Wout[q*16 + i];
        xs[tid] = s;
    }
    __syncthreads();
    if (tid < 128){
        const float* xs = (const float*)smraw;
        xn_out[blk*128 + tid] = xs[4*tid] + xs[4*tid+1] + xs[4*tid+2] + xs[4*tid+3] + bout[0];
    }
}

// ---------------- decoder step: MFMA bf16 ----------------
// LDS (bf16): Bihd@0(192x72) Bhhd@13824(192x72) A_x@27648(128x72) A_h@36864(128x136)
#define D_OFFBIH 0
#define D_OFFBHH 13824
#define D_OFFAX  27648
#define D_OFFAH  36864
#define D_SMEM   108544

__global__ __launch_bounds__(512, 2) void dec_step(
    const float* __restrict__ X, const unsigned short* __restrict__ decB,
    const float* __restrict__ Win, const float* __restrict__ bin,
    const float* __restrict__ bih, const float* __restrict__ bhh,
    const float* __restrict__ Wout, const float* __restrict__ bout,
    const float* __restrict__ h_in, float* __restrict__ h_out,
    const float* __restrict__ xn_in, float* __restrict__ xn_out,
    float* __restrict__ out, int t)
{
    extern __shared__ char smraw[];
    unsigned short* sm16 = (unsigned short*)smraw;
    const int tid  = threadIdx.x;
    const int lane = tid & 63;
    const int w    = __builtin_amdgcn_readfirstlane(tid >> 6);
    const int mt = w >> 1, jt = w & 1;
    const int blk = blockIdx.x;

    // P0a: B image memcpy (55296B)
    {
        const uint4* src = (const uint4*)decB;
        uint4* dst = (uint4*)smraw;
        for (int i = tid; i < 3456; i += 512) dst[i] = src[i];
    }
    // P0b: xin = [xn|X13..15] @ Win + bin -> A_x bf16 (each thread 16 cols of one node)
    {
        const int node = tid >> 2, c0 = (tid & 3)*16;
        const int node_g = blk*128 + node;
        const int b = node_g / NN, nloc = node_g - b*NN;
        const float* Xt = X + (size_t)(b*TT + HIST + t)*NN*FF;
        float x0 = xn_in[node_g];
        float x1 = Xt[nloc*FF + 13];
        float x2 = Xt[nloc*FF + 14];
        float x3 = Xt[nloc*FF + 15];
        unsigned int* ax32 = (unsigned int*)(sm16 + D_OFFAX);
        #pragma unroll
        for (int p=0; p<8; p++){
            int c = c0 + 2*p;
            float va = bin[c]   + x0*Win[c]     + x1*Win[64+c]   + x2*Win[128+c]   + x3*Win[192+c];
            float vb = bin[c+1] + x0*Win[c+1]   + x1*Win[64+c+1] + x2*Win[128+c+1] + x3*Win[192+c+1];
            ax32[(node*PB72 + c) >> 1] = (unsigned int)f2bf(va) | ((unsigned int)f2bf(vb) << 16);
        }
    }
    // P0c: h -> A_h [hi|lo]
    {
        const int node = tid >> 2, c0 = (tid & 3)*16;
        const float4* hp4 = (const float4*)(h_in + (size_t)(blk*128 + node)*64 + c0);
        unsigned int* ah32 = (unsigned int*)(sm16 + D_OFFAH);
        #pragma unroll
        for (int qq = 0; qq < 4; qq++){
            float4 v = hp4[qq];
            float vs[4] = {v.x, v.y, v.z, v.w};
            #pragma unroll
            for (int pp = 0; pp < 2; pp++){
                unsigned short h0 = f2bf(vs[2*pp]),   h1 = f2bf(vs[2*pp+1]);
                unsigned short l0 = f2bf(vs[2*pp]   - bf2f(h0));
                unsigned short l1 = f2bf(vs[2*pp+1] - bf2f(h1));
                int col = c0 + 4*qq + 2*pp;
                ah32[(node*PAS + col)      >> 1] = (unsigned int)h0 | ((unsigned int)h1 << 16);
                ah32[(node*PAS + 64 + col) >> 1] = (unsigned int)l0 | ((unsigned int)l1 << 16);
            }
        }
    }
    __syncthreads();

    // P2: GEMMs
    f16v accx[3] = {{},{},{}};
    f16v acch[3] = {{},{},{}};
    {
        const int rA = mt*32 + (lane & 31);
        const int ln = lane & 31;
        const int ke = (lane >> 5)*8;
        #pragma unroll
        for (int ks=0; ks<4; ks++){
            s8v a = *(const s8v*)(sm16 + D_OFFAX + rA*PB72 + ks*16 + ke);
            #pragma unroll
            for (int nt=0; nt<3; nt++){
                int NT = jt + nt*2;
                s8v b = *(const s8v*)(sm16 + D_OFFBIH + (NT*32 + ln)*PB72 + ks*16 + ke);
                accx[nt] = __builtin_amdgcn_mfma_f32_32x32x16_bf16(a, b, accx[nt], 0,0,0);
            }
        }
        #pragma unroll
        for (int ks=0; ks<4; ks++){
            s8v ah = *(const s8v*)(sm16 + D_OFFAH + rA*PAS      + ks*16 + ke);
            s8v al = *(const s8v*)(sm16 + D_OFFAH + rA*PAS + 64 + ks*16 + ke);
            #pragma unroll
            for (int nt=0; nt<3; nt++){
                int NT = jt + nt*2;
                s8v b = *(const s8v*)(sm16 + D_OFFBHH + (NT*32 + ln)*PB72 + ks*16 + ke);
                acch[nt] = __builtin_amdgcn_mfma_f32_32x32x16_bf16(ah, b, acch[nt], 0,0,0);
                acch[nt] = __builtin_amdgcn_mfma_f32_32x32x16_bf16(al, b, acch[nt], 0,0,0);
            }
        }
    }
    __syncthreads();

    // P3: epilogue
    {
        const int j = jt*32 + (lane & 31);
        const float br  = bih[j]     + bhh[j];
        const float bz  = bih[64+j]  + bhh[64+j];
        const float bin_ = bih[128+j];
        const float bhn  = bhh[128+j];
        float* hL = (float*)(smraw + D_OFFAH*2);
        #pragma unroll
        for (int reg=0; reg<16; reg++){
            int row = (reg&3) + 8*(reg>>2) + 4*(lane>>5);
            int node_l = mt*32 + row;
            size_t gidx = (size_t)(blk*128 + node_l)*64 + j;
            float r  = sigf(accx[0][reg] + acch[0][reg] + br);
            float z  = sigf(accx[1][reg] + acch[1][reg] + bz);
            float nn = tanhf_(accx[2][reg] + bin_ + r*(acch[2][reg] + bhn));
            float hp = (1.f - z)*nn + z*h_in[gidx];
            h_out[gidx] = hp;
            hL[node_l*68 + j] = hp;
        }
    }
    __syncthreads();

    // P4: xn + out
    {
        const float* hL = (const float*)(smraw + D_OFFAH*2);
        float* xs = (float*)smraw;
        const int node_l = tid >> 2, q = tid & 3;
        float s = 0.f;
        #pragma unroll
        for (int i=0;i<16;i++) s += hL[node_l*68 + q*16 + i] * Wout[q*16 + i];
        xs[tid] = s;
    }
    __syncthreads();
    if (tid < 128){
        const float* xs = (const float*)smraw;
        float v = xs[4*tid] + xs[4*tid+1] + xs[4*tid+2] + xs[4*tid+3] + bout[0];
        const int node_g = blk*128 + tid;
        const int b = node_g / NN, nloc = node_g - b*NN;
        xn_out[node_g] = v;
        out[(size_t)(b*FC + t)*NN + nloc] = v;
    }
}

extern "C" void kernel_launch(void* const* d_in, const int* in_sizes, int n_in,
                              void* d_out, int out_size, void* d_ws, size_t ws_size,
                              hipStream_t stream)
{
    const float* X     = (const float*)d_in[0];
    const float* y     = (const float*)d_in[1];
    const int*   ei    = (const int*)  d_in[2];
    const float* ew    = (const float*)d_in[3];
    const float* W_rel = (const float*)d_in[4];
    const float* b_rel = (const float*)d_in[5];
    const float* W_root= (const float*)d_in[6];
    const float* eWih  = (const float*)d_in[7];
    const float* eWhh  = (const float*)d_in[8];
    const float* ebih  = (const float*)d_in[9];
    const float* ebhh  = (const float*)d_in[10];
    const float* eWout = (const float*)d_in[11];
    const float* ebout = (const float*)d_in[12];
    const float* dWin  = (const float*)d_in[13];
    const float* dbin  = (const float*)d_in[14];
    const float* dWih  = (const float*)d_in[15];
    const float* dWhh  = (const float*)d_in[16];
    const float* dbih  = (const float*)d_in[17];
    const float* dbhh  = (const float*)d_in[18];
    const float* dWout = (const float*)d_in[19];
    const float* dbout = (const float*)d_in[20];
    float* out = (float*)d_out;

    // ws: aggs 52.2MB | h ping-pong 2x8.19MB | xn 2x128KB | encB 76.8KB | decB 55.3KB
    float* aggs = (float*)d_ws;
    float* h0 = aggs + (size_t)24*17*BN;
    float* h1 = h0 + (size_t)BN*HID;
    float* x0 = h1 + (size_t)BN*HID;
    float* x1 = x0 + BN;
    unsigned short* encB = (unsigned short*)(x1 + BN);
    unsigned short* decB = encB + 38400;

    hipMemsetAsync(h0, 0, (size_t)BN*HID*sizeof(float), stream);
    hipMemsetAsync(x0, 0, (size_t)BN*sizeof(float), stream);

    const int* esrc = ei;

    const int smA = (NN*FF + NN)*sizeof(float);
    hipFuncSetAttribute((const void*)agg_pre,
                        hipFuncAttributeMaxDynamicSharedMemorySize, smA);
    hipFuncSetAttribute((const void*)enc_step,
                        hipFuncAttributeMaxDynamicSharedMemorySize, E_SMEM);
    hipFuncSetAttribute((const void*)dec_step,
                        hipFuncAttributeMaxDynamicSharedMemorySize, D_SMEM);

    prep_weights<<<78, 256, 0, stream>>>(W_rel, W_root, eWih, eWhh, dWih, dWhh, encB, decB);
    agg_pre<<<dim3(BX,24), 1024, smA, stream>>>(X, y, esrc, ew, aggs);

    float* hin = h0; float* hout = h1;
    float* xin = x0; float* xout = x1;

    for (int t=0; t<HIST; t++){
        enc_step<<<250, 512, E_SMEM, stream>>>(X, y, esrc, ew, aggs, encB,
                                               b_rel, ebih, ebhh, eWout, ebout,
                                               hin, hout, xin, xout, t);
        float* tmp;
        tmp = hin; hin = hout; hout = tmp;
        tmp = xin; xin = xout; xout = tmp;
    }
    for (int t=0; t<FC; t++){
        dec_step<<<250, 512, D_SMEM, stream>>>(X, decB, dWin, dbin, dbih, dbhh,
                                               dWout, dbout,
                                               hin, hout, xin, xout, out, t);
        float* tmp;
        tmp = hin; hin = hout; hout = tmp;
        tmp = xin; xin = xout; xout = tmp;
    }
}